// Round 14
// baseline (2368.615 us; speedup 1.0000x reference)
//
#include <hip/hip_runtime.h>
#include <hip/hip_bf16.h>

// ChromaticTransportEvaluator — round 14.
// R13 audit: sinkhorn = 8840 cyc/pass, ~70% VMEM-return of 12 streamed
// K-chunks (384 KB), on only 128 of 256 CUs. This round: PAIR-SPLIT j-space
// across two blocks (256 blocks = all CUs). Each block owns 8 patches x 16
// j-tiles: K-slice 256 KB -> 8/16 chunks LDS-cached, stream 128 KB/pass.
// Cross-block u/v exchange = 4 KB/pass via double-buffered global staging +
// device-scope atomics (per-wave release fetch_add flags, acquire spin).
// u/v/hist stay in LDS so cache invalidation can't force refetch of them.
//
// mfma_f32_16x16x32_f16 layouts (shape-determined):
//   A[m][k]: m = lane&15, k = (lane>>4)*8 + reg
//   B[k][n]: n = lane&15, k = (lane>>4)*8 + reg
//   C/D:     col = lane&15, row = (lane>>4)*4 + reg

#define LAB_STRIDE 786432         // 4*3*256*256 floats per image-set
#define SP 520                    // f16 pitch for LDS u/v (16B-aligned rows)

typedef __attribute__((ext_vector_type(8))) _Float16 half8_t;
typedef __attribute__((ext_vector_type(4))) _Float16 half4_t;
typedef __attribute__((ext_vector_type(4))) float floatx4;

__device__ __forceinline__ float hw_exp2(float x) { return __builtin_amdgcn_exp2f(x); }
__device__ __forceinline__ float hw_log2(float x) { return __builtin_amdgcn_logf(x); }

__device__ __forceinline__ unsigned enc_f(float f) {
    unsigned u = __float_as_uint(f);
    return (u & 0x80000000u) ? ~u : (u | 0x80000000u);
}
__device__ __forceinline__ float dec_f(unsigned k) {
    unsigned u = (k & 0x80000000u) ? (k ^ 0x80000000u) : ~k;
    return __uint_as_float(u);
}

__device__ __forceinline__ float s2lin(float x) {
    x = fminf(fmaxf(x, 0.f), 1.f);
    return (x <= 0.04045f) ? (x * (1.f / 12.92f))
                           : hw_exp2(2.4f * hw_log2((x + 0.055f) * (1.f / 1.055f)));
}
__device__ __forceinline__ float cbrt_fast(float l) {
    return hw_exp2(0.33333333333f * hw_log2(fmaxf(l, 1e-12f)));
}

// Reduce per-block minmax (256 producer blocks per image) into lo/hi.
__device__ __forceinline__ void compute_lohi(
        const float* __restrict__ bmn, const float* __restrict__ bmx,
        int img, float lo[3], float hi[3]) {
    int lane = threadIdx.x & 63;
    for (int c = 0; c < 3; ++c) {
        float mn = 3.4e38f, mx = -3.4e38f;
        for (int i = lane; i < 256; i += 64) {
            mn = fminf(mn, bmn[(img * 256 + i) * 3 + c]);
            mx = fmaxf(mx, bmx[(img * 256 + i) * 3 + c]);
        }
        for (int s = 1; s < 64; s <<= 1) {
            mn = fminf(mn, __shfl_xor(mn, s));
            mx = fmaxf(mx, __shfl_xor(mx, s));
        }
        float l = mn - 0.01f, h = mx + 0.01f;
        if (h - l < 1e-4f) { l -= 0.05f; h += 0.05f; }
        lo[c] = l; hi[c] = h;
    }
}

// 512 blocks x 256 threads x 4 px (float4). img = blk>>8. 2 blocks/CU.
__global__ __launch_bounds__(256) void oklab_minmax_kernel(
        const float* __restrict__ ref, const float* __restrict__ tgt,
        float* __restrict__ lab, float* __restrict__ bmn, float* __restrict__ bmx) {
    int blk = blockIdx.x, tid = threadIdx.x;
    int img = blk >> 8;
    const float* src = img ? tgt : ref;
    float* dst = lab + img * LAB_STRIDE;

    __shared__ unsigned smin[3], smax[3];
    if (tid < 3) { smin[tid] = 0xFFFFFFFFu; smax[tid] = 0u; }
    __syncthreads();

    int px = (blk & 255) * 1024 + tid * 4;    // 0..262140, 4-aligned
    int bi = px >> 16, rem = px & 65535;      // all 4 px in the same image
    const float* s0 = src + (bi * 3) * 65536 + rem;
    float4 R4 = *(const float4*)(s0);
    float4 G4 = *(const float4*)(s0 + 65536);
    float4 B4 = *(const float4*)(s0 + 131072);

    float fmn[3] = {3.4e38f, 3.4e38f, 3.4e38f};
    float fmx[3] = {-3.4e38f, -3.4e38f, -3.4e38f};
    float Lo[4], Ao[4], Bo[4];
    const float* rp = &R4.x; const float* gp = &G4.x; const float* bp = &B4.x;
    #pragma unroll
    for (int e = 0; e < 4; ++e) {
        float r = s2lin(rp[e]);
        float g = s2lin(gp[e]);
        float b = s2lin(bp[e]);
        float l0 = fmaxf(0.4122214708f * r + 0.5363325363f * g + 0.0514459929f * b, 0.f);
        float l1 = fmaxf(0.2119034982f * r + 0.6806995451f * g + 0.1073969566f * b, 0.f);
        float l2 = fmaxf(0.0883024619f * r + 0.2817188376f * g + 0.6299787005f * b, 0.f);
        float g0 = (l0 > 0.f) ? cbrt_fast(l0) : 0.f;
        float g1 = (l1 > 0.f) ? cbrt_fast(l1) : 0.f;
        float g2 = (l2 > 0.f) ? cbrt_fast(l2) : 0.f;
        float L  = 0.2104542553f * g0 + 0.793617785f  * g1 - 0.0040720468f * g2;
        float A  = 1.9779984951f * g0 - 2.428592205f  * g1 + 0.4505937099f * g2;
        float Bv = 0.0259040371f * g0 + 0.7827717662f * g1 - 0.808675766f  * g2;
        Lo[e] = L; Ao[e] = A; Bo[e] = Bv;
        fmn[0] = fminf(fmn[0], L);  fmx[0] = fmaxf(fmx[0], L);
        fmn[1] = fminf(fmn[1], A);  fmx[1] = fmaxf(fmx[1], A);
        fmn[2] = fminf(fmn[2], Bv); fmx[2] = fmaxf(fmx[2], Bv);
    }
    float* d0 = dst + (bi * 3) * 65536 + rem;
    *(float4*)(d0)          = make_float4(Lo[0], Lo[1], Lo[2], Lo[3]);
    *(float4*)(d0 + 65536)  = make_float4(Ao[0], Ao[1], Ao[2], Ao[3]);
    *(float4*)(d0 + 131072) = make_float4(Bo[0], Bo[1], Bo[2], Bo[3]);

    for (int s = 1; s < 64; s <<= 1) {
        for (int c = 0; c < 3; ++c) {
            fmn[c] = fminf(fmn[c], __shfl_xor(fmn[c], s));
            fmx[c] = fmaxf(fmx[c], __shfl_xor(fmx[c], s));
        }
    }
    if ((tid & 63) == 0) {
        for (int c = 0; c < 3; ++c) {
            atomicMin(&smin[c], enc_f(fmn[c]));
            atomicMax(&smax[c], enc_f(fmx[c]));
        }
    }
    __syncthreads();
    if (tid < 3) {
        bmn[blk * 3 + tid] = dec_f(smin[tid]);
        bmx[blk * 3 + tid] = dec_f(smax[tid]);
    }
}

// 256 blocks x 256 thr: pack K + Kc as f16 B-fragments [kc][jt][lane][8].
// Block 0 also zeroes emd + pair flags (poisoned 0xAA by harness).
__global__ __launch_bounds__(256) void pack_k_kernel(
        const float* __restrict__ bmn, const float* __restrict__ bmx,
        _Float16* __restrict__ kmf, _Float16* __restrict__ kcf,
        float* __restrict__ emd, unsigned* __restrict__ flags) {
    int blk = blockIdx.x, tid = threadIdx.x;
    if (blk == 0) {
        #pragma unroll
        for (int i = 0; i < 4; ++i) emd[tid + i * 256] = 0.f;
        flags[tid] = 0u;
    }
    float lo0[3], hi0[3], lo1[3], hi1[3];
    compute_lohi(bmn, bmx, 0, lo0, hi0);
    compute_lohi(bmn, bmx, 1, lo1, hi1);
    float cen[3][8];
    for (int c = 0; c < 3; ++c)
        for (int k = 0; k < 8; ++k) {
            float t = (k + 0.5f) * 0.125f;
            cen[c][k] = 0.5f * ((lo0[c] + (hi0[c] - lo0[c]) * t)
                              + (lo1[c] + (hi1[c] - lo1[c]) * t));
        }
    int g = blk * 256 + tid;
    int half = g & 1, lane = (g >> 1) & 63, kc = (g >> 7) & 15, jt = g >> 11;
    int n = jt * 16 + (lane & 15);
    int kb = kc * 32 + ((lane >> 4) << 3) + half * 4;
    float n0 = cen[0][n >> 6], n1 = cen[1][(n >> 3) & 7], n2 = cen[2][n & 7];
    half4_t vm, vc;
    #pragma unroll
    for (int r = 0; r < 4; ++r) {
        int k = kb + r;
        float d0 = cen[0][k >> 6] - n0;
        float d1 = cen[1][(k >> 3) & 7] - n1;
        float d2 = cen[2][k & 7] - n2;
        float dd = d0 * d0 + d1 * d1 + d2 * d2;
        float cost = (dd > 0.f) ? __fsqrt_rn(dd) : 0.f;
        float kv = hw_exp2(-cost * 14.426950408889634f);   // exp(-cost/0.1)
        vm[r] = (_Float16)kv;
        vc[r] = (_Float16)(kv * cost);
    }
    int base = ((kc * 32 + jt) * 64 + lane) * 8 + half * 4;
    *(half4_t*)(kmf + base) = vm;
    *(half4_t*)(kcf + base) = vc;
}

// 256 blocks x 512 threads. b = blockIdx: pg = b>>1 (8 patches), jh = b&1
// (j-half, 16 j-tiles). K-slice: kc 0..7 LDS (128 KB), kc 8..15 streamed
// (128 KB/pass). Per pass: compute own j-half of the update, exchange the
// 4 KB half with partner block (b^1) via global xbuf (parity double-buffer,
// device-scope atomics, per-wave release flags + acquire spin).
__global__ __launch_bounds__(512) void sinkhorn_kernel(
        const float* __restrict__ lab,
        const float* __restrict__ bmn, const float* __restrict__ bmx,
        const _Float16* __restrict__ kmf, const _Float16* __restrict__ kcf,
        float* __restrict__ emd, unsigned* __restrict__ flags,
        unsigned short* __restrict__ xbuf) {
    __shared__ __align__(16) _Float16 U[8 * SP], V[8 * SP];
    __shared__ __align__(16) _Float16 Kc8[65536];   // own j-half, kc 0..7 (128 KB)
    __shared__ float ebuf[8];
    int tid = threadIdx.x;
    int b = blockIdx.x;
    int pg = b >> 1, jh = b & 1;
    int wave = tid >> 6, lane = tid & 63;
    int pbase = pg * 8;

    int mrow = lane & 15;            // A row (patch)
    int kgrp = (lane >> 4) << 3;     // A k-offset
    int jt0 = jh * 16 + wave * 2;    // first of 2 global j-tiles for this wave
    int rq = lane >> 4;              // C row-quad
    int colc = lane & 15;            // C col

    // lo/hi + inverse bin width per image
    float lo_[2][3], inv_[2][3];
    {
        float lo0[3], hi0[3], lo1[3], hi1[3];
        compute_lohi(bmn, bmx, 0, lo0, hi0);
        compute_lohi(bmn, bmx, 1, lo1, hi1);
        for (int c = 0; c < 3; ++c) {
            lo_[0][c] = lo0[c]; inv_[0][c] = 8.f / (hi0[c] - lo0[c]);
            lo_[1][c] = lo1[c]; inv_[1][c] = 8.f / (hi1[c] - lo1[c]);
        }
    }

    // ---- Prologue: build 16 histograms (2 img x 8 patches), 2 per round,
    // in LDS scratch (reusing Kc8 region), pull this thread's values. ----
    float hreg[2][2][4];             // [img][q][r]
    unsigned* scr = (unsigned*)Kc8;  // 2 x 512 bins
    for (int s = 0; s < 8; ++s) {
        scr[tid] = 0u; scr[tid + 512] = 0u;
        __syncthreads();
        int grp = tid >> 8;                   // 0/1
        int pair = s * 2 + grp;               // 0..15
        int img = pair >> 3, pl = pair & 7;
        int p = pbase + pl;
        int bb = p >> 8, ph = (p >> 4) & 15, pw = p & 15;
        int px = tid & 255;
        int y = px >> 4, x = px & 15;
        int rem = (ph * 16 + y) * 256 + pw * 16 + x;
        const float* lb = lab + img * LAB_STRIDE + bb * 3 * 65536 + rem;
        int bin = 0;
        #pragma unroll
        for (int c = 0; c < 3; ++c) {
            float v = lb[c * 65536];
            int k = (int)floorf((v - lo_[img][c]) * inv_[img][c]);
            k = min(max(k, 0), 7);
            bin = bin * 8 + k;
        }
        atomicAdd(&scr[grp * 512 + bin], 1u);
        __syncthreads();
        #pragma unroll
        for (int g2 = 0; g2 < 2; ++g2) {
            int pr2 = s * 2 + g2;
            int im2 = pr2 >> 3, pl2 = pr2 & 7;
            if (rq < 2 && (pl2 >> 2) == rq) {
                int r = pl2 & 3;
                #pragma unroll
                for (int q = 0; q < 2; ++q)
                    hreg[im2][q][r] = (float)scr[g2 * 512 + (jt0 + q) * 16 + colc]
                                    * (1.f / 256.f);
            }
        }
        __syncthreads();
    }
    if (rq >= 2)
        for (int i2 = 0; i2 < 2; ++i2)
            for (int q = 0; q < 2; ++q)
                for (int r = 0; r < 4; ++r) hreg[i2][q][r] = 0.f;

    // u = ones; load own-half K chunks 0..7 into LDS
    for (int i = tid; i < 8 * SP; i += 512) U[i] = (_Float16)1.0f;
    for (int i = tid; i < 8192; i += 512) {
        int kc = i >> 10, rem2 = i & 1023;
        int ltj = rem2 >> 6, ln = rem2 & 63;
        *(half8_t*)(Kc8 + i * 8) =
            *(const half8_t*)(kmf + (((kc * 32 + jh * 16 + ltj) * 64 + ln) * 8));
    }
    if (tid < 8) ebuf[tid] = 0.f;
    __syncthreads();

    int partner = b ^ 1;
    int pcb = (jh ^ 1) * 256;        // partner's column base in U/V
    unsigned short* xb_me = xbuf + b * 2048;
    const unsigned* xb_pa32 = (const unsigned*)(xbuf + partner * 2048);
    const int PAR_OFF = 256 * 2048;  // parity stride (elements)

    for (int h = 0; h < 40; ++h) {
        const _Float16* S = (h & 1) ? V : U;
        _Float16* D = (h & 1) ? U : V;
        int par = (h & 1) * PAR_OFF;
        floatx4 acc[2] = {{0,0,0,0},{0,0,0,0}};
        #pragma unroll
        for (int kc = 0; kc < 8; ++kc) {       // LDS-cached chunks
            half8_t a = *(const half8_t*)&S[mrow * SP + kc * 32 + kgrp];
            #pragma unroll
            for (int q = 0; q < 2; ++q) {
                half8_t bfr = *(const half8_t*)&Kc8[((kc * 16 + wave * 2 + q) * 64 + lane) * 8];
                acc[q] = __builtin_amdgcn_mfma_f32_16x16x32_f16(a, bfr, acc[q], 0, 0, 0);
            }
        }
        #pragma unroll
        for (int kc = 8; kc < 16; ++kc) {      // L2-streamed chunks
            half8_t a = *(const half8_t*)&S[mrow * SP + kc * 32 + kgrp];
            const _Float16* bbp = kmf + ((kc * 32 + jt0) * 64 + lane) * 8;
            #pragma unroll
            for (int q = 0; q < 2; ++q) {
                half8_t bfr = *(const half8_t*)(bbp + q * 512);
                acc[q] = __builtin_amdgcn_mfma_f32_16x16x32_f16(a, bfr, acc[q], 0, 0, 0);
            }
        }
        if (rq < 2) {
            const int hi_sel = (h & 1) ? 0 : 1;
            #pragma unroll
            for (int q = 0; q < 2; ++q) {
                int col = (jt0 + q) * 16 + colc;       // global col (own half)
                int colL = col - jh * 256;             // 0..255
                #pragma unroll
                for (int r = 0; r < 4; ++r) {
                    int row = rq * 4 + r;
                    float d = hreg[hi_sel][q][r] / (acc[q][r] + 1e-6f);
                    _Float16 hv = (_Float16)fminf(d, 60000.f);
                    D[row * SP + col] = hv;
                    __hip_atomic_store(xb_me + par + row * 256 + colL,
                                       __builtin_bit_cast(unsigned short, hv),
                                       __ATOMIC_RELAXED, __HIP_MEMORY_SCOPE_AGENT);
                }
            }
        }
        if (lane == 0)
            __hip_atomic_fetch_add(&flags[b], 1u, __ATOMIC_RELEASE,
                                   __HIP_MEMORY_SCOPE_AGENT);
        unsigned want = 8u * (h + 1);
        while (__hip_atomic_load(&flags[partner], __ATOMIC_ACQUIRE,
                                 __HIP_MEMORY_SCOPE_AGENT) < want)
            __builtin_amdgcn_s_sleep(2);
        // pull partner half: 1024 u32, 2 per thread
        {
            const unsigned* src32 = xb_pa32 + (par >> 1);
            #pragma unroll
            for (int t2 = 0; t2 < 2; ++t2) {
                int k32 = tid * 2 + t2;
                unsigned v32 = __hip_atomic_load(src32 + k32, __ATOMIC_RELAXED,
                                                 __HIP_MEMORY_SCOPE_AGENT);
                int row = k32 >> 7, colL = (k32 & 127) * 2;
                *(unsigned*)&D[row * SP + pcb + colL] = v32;
            }
        }
        __syncthreads();
    }

    // EMD: acc = u @ Kc over own j-half (stream kcf), dot with v, reduce,
    // global atomicAdd per patch (partner adds its half).
    {
        floatx4 acc[2] = {{0,0,0,0},{0,0,0,0}};
        #pragma unroll
        for (int kc = 0; kc < 16; ++kc) {
            half8_t a = *(const half8_t*)&U[mrow * SP + kc * 32 + kgrp];
            const _Float16* bbp = kcf + ((kc * 32 + jt0) * 64 + lane) * 8;
            #pragma unroll
            for (int q = 0; q < 2; ++q) {
                half8_t bfr = *(const half8_t*)(bbp + q * 512);
                acc[q] = __builtin_amdgcn_mfma_f32_16x16x32_f16(a, bfr, acc[q], 0, 0, 0);
            }
        }
        float pe[4] = {0.f, 0.f, 0.f, 0.f};
        if (rq < 2) {
            #pragma unroll
            for (int q = 0; q < 2; ++q) {
                int col = (jt0 + q) * 16 + colc;
                #pragma unroll
                for (int r = 0; r < 4; ++r)
                    pe[r] += acc[q][r] * (float)V[(rq * 4 + r) * SP + col];
            }
        }
        for (int s = 1; s < 16; s <<= 1) {
            #pragma unroll
            for (int r = 0; r < 4; ++r) pe[r] += __shfl_xor(pe[r], s);
        }
        if (colc == 0 && rq < 2) {
            #pragma unroll
            for (int r = 0; r < 4; ++r)
                atomicAdd(&ebuf[rq * 4 + r], pe[r]);
        }
        __syncthreads();
        if (tid < 8) atomicAdd(&emd[pbase + tid], ebuf[tid]);
    }
}

// (4,1,16,16) -> (4,1,256,256), half-pixel bilinear, edge clamp, nan_to_num
__global__ __launch_bounds__(256) void upsample_kernel(
        const float* __restrict__ emd, float* __restrict__ out) {
    #pragma unroll
    for (int k = 0; k < 4; ++k) {
        int idx = blockIdx.x * 1024 + k * 256 + threadIdx.x;   // 0..262143
        int b = idx >> 16;
        int rem = idx & 65535;
        int y = rem >> 8, x = rem & 255;
        float sy = (y + 0.5f) * 0.0625f - 0.5f;
        float sx = (x + 0.5f) * 0.0625f - 0.5f;
        float fy0 = floorf(sy), fx0 = floorf(sx);
        float fy = sy - fy0, fx = sx - fx0;
        int y0 = (int)fy0, x0 = (int)fx0;
        int y0c = min(max(y0, 0), 15), y1c = min(max(y0 + 1, 0), 15);
        int x0c = min(max(x0, 0), 15), x1c = min(max(x0 + 1, 0), 15);
        const float* e = emd + b * 256;
        float v00 = e[y0c * 16 + x0c], v01 = e[y0c * 16 + x1c];
        float v10 = e[y1c * 16 + x0c], v11 = e[y1c * 16 + x1c];
        if (!__builtin_isfinite(v00)) v00 = 0.f;
        if (!__builtin_isfinite(v01)) v01 = 0.f;
        if (!__builtin_isfinite(v10)) v10 = 0.f;
        if (!__builtin_isfinite(v11)) v11 = 0.f;
        out[idx] = (1.f - fy) * ((1.f - fx) * v00 + fx * v01)
                 + fy * ((1.f - fx) * v10 + fx * v11);
    }
}

extern "C" void kernel_launch(void* const* d_in, const int* in_sizes, int n_in,
                              void* d_out, int out_size, void* d_ws, size_t ws_size,
                              hipStream_t stream) {
    const float* ref = (const float*)d_in[0];
    const float* tgt = (const float*)d_in[1];
    float* out = (float*)d_out;

    float* lab = (float*)d_ws;                        // 1,572,864 f32
    float* bmn = lab + 2 * LAB_STRIDE;                // 1536 f32
    float* bmx = bmn + 1536;                          // 1536 f32
    float* emd = bmx + 1536;                          // 1024 f32
    _Float16* kmf = (_Float16*)(emd + 1024);          // 262,144 f16 (16B-aligned)
    _Float16* kcf = kmf + 262144;                     // 262,144 f16
    unsigned* flags = (unsigned*)(kcf + 262144);      // 256 u32
    unsigned short* xbuf = (unsigned short*)(flags + 256); // 2 x 256 x 2048 f16

    oklab_minmax_kernel<<<512, 256, 0, stream>>>(ref, tgt, lab, bmn, bmx);
    pack_k_kernel<<<256, 256, 0, stream>>>(bmn, bmx, kmf, kcf, emd, flags);
    sinkhorn_kernel<<<256, 512, 0, stream>>>(lab, bmn, bmx, kmf, kcf,
                                             emd, flags, xbuf);
    upsample_kernel<<<256, 256, 0, stream>>>(emd, out);
}

// Round 15
// 212.359 us; speedup vs baseline: 11.1538x; 11.1538x over previous
//
#include <hip/hip_runtime.h>
#include <hip/hip_bf16.h>

// ChromaticTransportEvaluator — round 15: REVERT to R13 (212.8us known-good).
// R14 post-mortem: pair-split j-space with per-pass cross-block flag
// handshake ran 15x slower (MfmaUtil 0.74% — all spin). With R5: ANY
// fine-grained inter-block sync loses 10-100x on MI355X. Avenue closed.
// Sinkhorn ledger: byte cuts neutral (R11), reg-pinning refused by allocator
// (R8-10), more waves -> VGPR collapse (R12), j-split -> sync-bound (R14).
// Structure: 41 passes x 384 KB K-stream/CU at ~56-64 B/cyc VMEM return
// ~= 105us floor; we run 151us (~70% of port). Remaining ~60us is 4-dispatch
// overhead + small kernels.
//
// mfma_f32_16x16x32_f16 layouts (shape-determined):
//   A[m][k]: m = lane&15, k = (lane>>4)*8 + reg
//   B[k][n]: n = lane&15, k = (lane>>4)*8 + reg
//   C/D:     col = lane&15, row = (lane>>4)*4 + reg

#define LAB_STRIDE 786432         // 4*3*256*256 floats per image-set
#define SP 520                    // f16 pitch for LDS u/v (16B-aligned rows)

typedef __attribute__((ext_vector_type(8))) _Float16 half8_t;
typedef __attribute__((ext_vector_type(4))) _Float16 half4_t;
typedef __attribute__((ext_vector_type(4))) float floatx4;

__device__ __forceinline__ float hw_exp2(float x) { return __builtin_amdgcn_exp2f(x); }
__device__ __forceinline__ float hw_log2(float x) { return __builtin_amdgcn_logf(x); }

__device__ __forceinline__ unsigned enc_f(float f) {
    unsigned u = __float_as_uint(f);
    return (u & 0x80000000u) ? ~u : (u | 0x80000000u);
}
__device__ __forceinline__ float dec_f(unsigned k) {
    unsigned u = (k & 0x80000000u) ? (k ^ 0x80000000u) : ~k;
    return __uint_as_float(u);
}

__device__ __forceinline__ float s2lin(float x) {
    x = fminf(fmaxf(x, 0.f), 1.f);
    return (x <= 0.04045f) ? (x * (1.f / 12.92f))
                           : hw_exp2(2.4f * hw_log2((x + 0.055f) * (1.f / 1.055f)));
}
__device__ __forceinline__ float cbrt_fast(float l) {
    return hw_exp2(0.33333333333f * hw_log2(fmaxf(l, 1e-12f)));
}

// Reduce per-block minmax (256 producer blocks per image) into lo/hi.
__device__ __forceinline__ void compute_lohi(
        const float* __restrict__ bmn, const float* __restrict__ bmx,
        int img, float lo[3], float hi[3]) {
    int lane = threadIdx.x & 63;
    for (int c = 0; c < 3; ++c) {
        float mn = 3.4e38f, mx = -3.4e38f;
        for (int i = lane; i < 256; i += 64) {
            mn = fminf(mn, bmn[(img * 256 + i) * 3 + c]);
            mx = fmaxf(mx, bmx[(img * 256 + i) * 3 + c]);
        }
        for (int s = 1; s < 64; s <<= 1) {
            mn = fminf(mn, __shfl_xor(mn, s));
            mx = fmaxf(mx, __shfl_xor(mx, s));
        }
        float l = mn - 0.01f, h = mx + 0.01f;
        if (h - l < 1e-4f) { l -= 0.05f; h += 0.05f; }
        lo[c] = l; hi[c] = h;
    }
}

// 512 blocks x 256 threads x 4 px (float4). img = blk>>8. 2 blocks/CU.
__global__ __launch_bounds__(256) void oklab_minmax_kernel(
        const float* __restrict__ ref, const float* __restrict__ tgt,
        float* __restrict__ lab, float* __restrict__ bmn, float* __restrict__ bmx) {
    int blk = blockIdx.x, tid = threadIdx.x;
    int img = blk >> 8;
    const float* src = img ? tgt : ref;
    float* dst = lab + img * LAB_STRIDE;

    __shared__ unsigned smin[3], smax[3];
    if (tid < 3) { smin[tid] = 0xFFFFFFFFu; smax[tid] = 0u; }
    __syncthreads();

    int px = (blk & 255) * 1024 + tid * 4;    // 0..262140, 4-aligned
    int bi = px >> 16, rem = px & 65535;      // all 4 px in the same image
    const float* s0 = src + (bi * 3) * 65536 + rem;
    float4 R4 = *(const float4*)(s0);
    float4 G4 = *(const float4*)(s0 + 65536);
    float4 B4 = *(const float4*)(s0 + 131072);

    float fmn[3] = {3.4e38f, 3.4e38f, 3.4e38f};
    float fmx[3] = {-3.4e38f, -3.4e38f, -3.4e38f};
    float Lo[4], Ao[4], Bo[4];
    const float* rp = &R4.x; const float* gp = &G4.x; const float* bp = &B4.x;
    #pragma unroll
    for (int e = 0; e < 4; ++e) {
        float r = s2lin(rp[e]);
        float g = s2lin(gp[e]);
        float b = s2lin(bp[e]);
        float l0 = fmaxf(0.4122214708f * r + 0.5363325363f * g + 0.0514459929f * b, 0.f);
        float l1 = fmaxf(0.2119034982f * r + 0.6806995451f * g + 0.1073969566f * b, 0.f);
        float l2 = fmaxf(0.0883024619f * r + 0.2817188376f * g + 0.6299787005f * b, 0.f);
        float g0 = (l0 > 0.f) ? cbrt_fast(l0) : 0.f;
        float g1 = (l1 > 0.f) ? cbrt_fast(l1) : 0.f;
        float g2 = (l2 > 0.f) ? cbrt_fast(l2) : 0.f;
        float L  = 0.2104542553f * g0 + 0.793617785f  * g1 - 0.0040720468f * g2;
        float A  = 1.9779984951f * g0 - 2.428592205f  * g1 + 0.4505937099f * g2;
        float Bv = 0.0259040371f * g0 + 0.7827717662f * g1 - 0.808675766f  * g2;
        Lo[e] = L; Ao[e] = A; Bo[e] = Bv;
        fmn[0] = fminf(fmn[0], L);  fmx[0] = fmaxf(fmx[0], L);
        fmn[1] = fminf(fmn[1], A);  fmx[1] = fmaxf(fmx[1], A);
        fmn[2] = fminf(fmn[2], Bv); fmx[2] = fmaxf(fmx[2], Bv);
    }
    float* d0 = dst + (bi * 3) * 65536 + rem;
    *(float4*)(d0)          = make_float4(Lo[0], Lo[1], Lo[2], Lo[3]);
    *(float4*)(d0 + 65536)  = make_float4(Ao[0], Ao[1], Ao[2], Ao[3]);
    *(float4*)(d0 + 131072) = make_float4(Bo[0], Bo[1], Bo[2], Bo[3]);

    for (int s = 1; s < 64; s <<= 1) {
        for (int c = 0; c < 3; ++c) {
            fmn[c] = fminf(fmn[c], __shfl_xor(fmn[c], s));
            fmx[c] = fmaxf(fmx[c], __shfl_xor(fmx[c], s));
        }
    }
    if ((tid & 63) == 0) {
        for (int c = 0; c < 3; ++c) {
            atomicMin(&smin[c], enc_f(fmn[c]));
            atomicMax(&smax[c], enc_f(fmx[c]));
        }
    }
    __syncthreads();
    if (tid < 3) {
        bmn[blk * 3 + tid] = dec_f(smin[tid]);
        bmx[blk * 3 + tid] = dec_f(smax[tid]);
    }
}

// 256 blocks x 256 thr: pack K=exp(-cost/0.1) and Kc=K*cost as f16
// B-fragments in [kc][jt][lane][8] order (4 entries/thread).
__global__ __launch_bounds__(256) void pack_k_kernel(
        const float* __restrict__ bmn, const float* __restrict__ bmx,
        _Float16* __restrict__ kmf, _Float16* __restrict__ kcf) {
    int blk = blockIdx.x, tid = threadIdx.x;
    float lo0[3], hi0[3], lo1[3], hi1[3];
    compute_lohi(bmn, bmx, 0, lo0, hi0);
    compute_lohi(bmn, bmx, 1, lo1, hi1);
    float cen[3][8];
    for (int c = 0; c < 3; ++c)
        for (int k = 0; k < 8; ++k) {
            float t = (k + 0.5f) * 0.125f;
            cen[c][k] = 0.5f * ((lo0[c] + (hi0[c] - lo0[c]) * t)
                              + (lo1[c] + (hi1[c] - lo1[c]) * t));
        }
    int g = blk * 256 + tid;
    int half = g & 1, lane = (g >> 1) & 63, kc = (g >> 7) & 15, jt = g >> 11;
    int n = jt * 16 + (lane & 15);
    int kb = kc * 32 + ((lane >> 4) << 3) + half * 4;
    float n0 = cen[0][n >> 6], n1 = cen[1][(n >> 3) & 7], n2 = cen[2][n & 7];
    half4_t vm, vc;
    #pragma unroll
    for (int r = 0; r < 4; ++r) {
        int k = kb + r;
        float d0 = cen[0][k >> 6] - n0;
        float d1 = cen[1][(k >> 3) & 7] - n1;
        float d2 = cen[2][k & 7] - n2;
        float dd = d0 * d0 + d1 * d1 + d2 * d2;
        float cost = (dd > 0.f) ? __fsqrt_rn(dd) : 0.f;
        float kv = hw_exp2(-cost * 14.426950408889634f);   // exp(-cost/0.1)
        vm[r] = (_Float16)kv;
        vc[r] = (_Float16)(kv * cost);
    }
    int base = ((kc * 32 + jt) * 64 + lane) * 8 + half * 4;
    *(half4_t*)(kmf + base) = vm;
    *(half4_t*)(kcf + base) = vc;
}

// 128 blocks x 512 threads (8 waves), 1 block/CU. Block owns 8 patches:
// prologue builds both histograms from lab (LDS scratch -> registers),
// then 40 half-iterations with K kc 0..3 in LDS (128 KB) and kc 4..15
// streamed from L2 (384 KB/pass), then EMD. Wave w owns j-cols [w*64,+64).
__global__ __launch_bounds__(512) void sinkhorn_kernel(
        const float* __restrict__ lab,
        const float* __restrict__ bmn, const float* __restrict__ bmx,
        const _Float16* __restrict__ kmf, const _Float16* __restrict__ kcf,
        float* __restrict__ emd) {
    __shared__ __align__(16) _Float16 U[8 * SP], V[8 * SP];
    __shared__ __align__(16) _Float16 Kc4[65536];   // kc 0..3 fragments, 128 KB
    __shared__ float ebuf[8];
    int tid = threadIdx.x;
    int wave = tid >> 6, lane = tid & 63;
    int pbase = blockIdx.x * 8;

    int mrow = lane & 15;          // A row (patch)
    int kgrp = (lane >> 4) << 3;   // A k-offset
    int jt0 = wave * 4;            // first of 4 j-tiles for this wave
    int rq = lane >> 4;            // C row-quad
    int colc = lane & 15;          // C col

    // lo/hi + inverse bin width per image
    float lo_[2][3], inv_[2][3];
    {
        float lo0[3], hi0[3], lo1[3], hi1[3];
        compute_lohi(bmn, bmx, 0, lo0, hi0);
        compute_lohi(bmn, bmx, 1, lo1, hi1);
        for (int c = 0; c < 3; ++c) {
            lo_[0][c] = lo0[c]; inv_[0][c] = 8.f / (hi0[c] - lo0[c]);
            lo_[1][c] = lo1[c]; inv_[1][c] = 8.f / (hi1[c] - lo1[c]);
        }
    }

    // ---- Prologue: build 16 histograms (2 img x 8 patches), 2 per round,
    // in LDS scratch (reusing Kc4 region), pull this thread's 32 values. ----
    float hreg[2][4][4];           // [img][q][r], rows rq*4+r, cols (jt0+q)*16+colc
    unsigned* scr = (unsigned*)Kc4;  // 2 x 512 bins
    for (int s = 0; s < 8; ++s) {
        scr[tid] = 0u; scr[tid + 512] = 0u;
        __syncthreads();
        int grp = tid >> 8;                   // 0/1
        int pair = s * 2 + grp;               // 0..15
        int img = pair >> 3, pl = pair & 7;
        int p = pbase + pl;
        int b = p >> 8, ph = (p >> 4) & 15, pw = p & 15;
        int px = tid & 255;
        int y = px >> 4, x = px & 15;
        int rem = (ph * 16 + y) * 256 + pw * 16 + x;
        const float* lb = lab + img * LAB_STRIDE + b * 3 * 65536 + rem;
        int bin = 0;
        #pragma unroll
        for (int c = 0; c < 3; ++c) {
            float v = lb[c * 65536];
            int k = (int)floorf((v - lo_[img][c]) * inv_[img][c]);
            k = min(max(k, 0), 7);
            bin = bin * 8 + k;
        }
        atomicAdd(&scr[grp * 512 + bin], 1u);
        __syncthreads();
        #pragma unroll
        for (int g2 = 0; g2 < 2; ++g2) {
            int pr2 = s * 2 + g2;
            int im2 = pr2 >> 3, pl2 = pr2 & 7;
            if (rq < 2 && (pl2 >> 2) == rq) {
                int r = pl2 & 3;
                #pragma unroll
                for (int q = 0; q < 4; ++q)
                    hreg[im2][q][r] = (float)scr[g2 * 512 + (jt0 + q) * 16 + colc]
                                    * (1.f / 256.f);
            }
        }
        __syncthreads();
    }
    if (rq >= 2)
        for (int i2 = 0; i2 < 2; ++i2)
            for (int q = 0; q < 4; ++q)
                for (int r = 0; r < 4; ++r) hreg[i2][q][r] = 0.f;

    // u = ones; load K chunks 0..3 into LDS
    for (int i = tid; i < 8 * SP; i += 512) U[i] = (_Float16)1.0f;
    for (int i = tid; i < 16384; i += 512)
        *(half8_t*)(Kc4 + i * 8) = *(const half8_t*)(kmf + i * 8);
    if (tid < 8) ebuf[tid] = 0.f;
    __syncthreads();

    for (int h = 0; h < 40; ++h) {
        const _Float16* S = (h & 1) ? V : U;
        _Float16* D = (h & 1) ? U : V;
        floatx4 acc[4] = {{0,0,0,0},{0,0,0,0},{0,0,0,0},{0,0,0,0}};
        #pragma unroll
        for (int kc = 0; kc < 4; ++kc) {       // LDS-cached chunks
            half8_t a = *(const half8_t*)&S[mrow * SP + kc * 32 + kgrp];
            #pragma unroll
            for (int q = 0; q < 4; ++q) {
                half8_t b = *(const half8_t*)&Kc4[((kc * 32 + jt0 + q) * 64 + lane) * 8];
                acc[q] = __builtin_amdgcn_mfma_f32_16x16x32_f16(a, b, acc[q], 0, 0, 0);
            }
        }
        #pragma unroll
        for (int kc = 4; kc < 16; ++kc) {      // L2-streamed chunks
            half8_t a = *(const half8_t*)&S[mrow * SP + kc * 32 + kgrp];
            const _Float16* bb = kmf + ((kc * 32 + jt0) * 64 + lane) * 8;
            #pragma unroll
            for (int q = 0; q < 4; ++q) {
                half8_t b = *(const half8_t*)(bb + q * 512);
                acc[q] = __builtin_amdgcn_mfma_f32_16x16x32_f16(a, b, acc[q], 0, 0, 0);
            }
        }
        if (rq < 2) {
            const int hi_sel = (h & 1) ? 0 : 1;   // even: v-update uses ht (img1)
            #pragma unroll
            for (int q = 0; q < 4; ++q) {
                int col = (jt0 + q) * 16 + colc;
                #pragma unroll
                for (int r = 0; r < 4; ++r) {
                    int row = rq * 4 + r;
                    float d = hreg[hi_sel][q][r] / (acc[q][r] + 1e-6f);
                    D[row * SP + col] = (_Float16)fminf(d, 60000.f);
                }
            }
        }
        __syncthreads();
    }

    // EMD: acc = u @ Kc (f16, full L2 stream once), dot with v, reduce.
    {
        floatx4 acc[4] = {{0,0,0,0},{0,0,0,0},{0,0,0,0},{0,0,0,0}};
        #pragma unroll
        for (int kc = 0; kc < 16; ++kc) {
            half8_t a = *(const half8_t*)&U[mrow * SP + kc * 32 + kgrp];
            const _Float16* bb = kcf + ((kc * 32 + jt0) * 64 + lane) * 8;
            #pragma unroll
            for (int q = 0; q < 4; ++q) {
                half8_t b = *(const half8_t*)(bb + q * 512);
                acc[q] = __builtin_amdgcn_mfma_f32_16x16x32_f16(a, b, acc[q], 0, 0, 0);
            }
        }
        float pe[4] = {0.f, 0.f, 0.f, 0.f};
        if (rq < 2) {
            #pragma unroll
            for (int q = 0; q < 4; ++q) {
                int col = (jt0 + q) * 16 + colc;
                #pragma unroll
                for (int r = 0; r < 4; ++r)
                    pe[r] += acc[q][r] * (float)V[(rq * 4 + r) * SP + col];
            }
        }
        for (int s = 1; s < 16; s <<= 1) {
            #pragma unroll
            for (int r = 0; r < 4; ++r) pe[r] += __shfl_xor(pe[r], s);
        }
        if (colc == 0 && rq < 2) {
            #pragma unroll
            for (int r = 0; r < 4; ++r)
                atomicAdd(&ebuf[rq * 4 + r], pe[r]);
        }
        __syncthreads();
        if (tid < 8) {
            float e = ebuf[tid];
            emd[pbase + tid] = __builtin_isfinite(e) ? e : 0.f;
        }
    }
}

// (4,1,16,16) -> (4,1,256,256), half-pixel bilinear, edge clamp
__global__ __launch_bounds__(256) void upsample_kernel(
        const float* __restrict__ emd, float* __restrict__ out) {
    #pragma unroll
    for (int k = 0; k < 4; ++k) {
        int idx = blockIdx.x * 1024 + k * 256 + threadIdx.x;   // 0..262143
        int b = idx >> 16;
        int rem = idx & 65535;
        int y = rem >> 8, x = rem & 255;
        float sy = (y + 0.5f) * 0.0625f - 0.5f;
        float sx = (x + 0.5f) * 0.0625f - 0.5f;
        float fy0 = floorf(sy), fx0 = floorf(sx);
        float fy = sy - fy0, fx = sx - fx0;
        int y0 = (int)fy0, x0 = (int)fx0;
        int y0c = min(max(y0, 0), 15), y1c = min(max(y0 + 1, 0), 15);
        int x0c = min(max(x0, 0), 15), x1c = min(max(x0 + 1, 0), 15);
        const float* e = emd + b * 256;
        float v00 = e[y0c * 16 + x0c], v01 = e[y0c * 16 + x1c];
        float v10 = e[y1c * 16 + x0c], v11 = e[y1c * 16 + x1c];
        out[idx] = (1.f - fy) * ((1.f - fx) * v00 + fx * v01)
                 + fy * ((1.f - fx) * v10 + fx * v11);
    }
}

extern "C" void kernel_launch(void* const* d_in, const int* in_sizes, int n_in,
                              void* d_out, int out_size, void* d_ws, size_t ws_size,
                              hipStream_t stream) {
    const float* ref = (const float*)d_in[0];
    const float* tgt = (const float*)d_in[1];
    float* out = (float*)d_out;

    float* lab = (float*)d_ws;                        // 1,572,864 f32
    float* bmn = lab + 2 * LAB_STRIDE;                // 1536 f32
    float* bmx = bmn + 1536;                          // 1536 f32
    float* emd = bmx + 1536;                          // 1024 f32
    _Float16* kmf = (_Float16*)(emd + 1024);          // 262,144 f16 (16B-aligned)
    _Float16* kcf = kmf + 262144;                     // 262,144 f16

    oklab_minmax_kernel<<<512, 256, 0, stream>>>(ref, tgt, lab, bmn, bmx);
    pack_k_kernel<<<256, 256, 0, stream>>>(bmn, bmx, kmf, kcf);
    sinkhorn_kernel<<<128, 512, 0, stream>>>(lab, bmn, bmx, kmf, kcf, emd);
    upsample_kernel<<<256, 256, 0, stream>>>(emd, out);
}